// Round 1
// baseline (996.882 us; speedup 1.0000x reference)
//
#include <hip/hip_runtime.h>
#include <hip/hip_bf16.h>

typedef _Float16 f16x8 __attribute__((ext_vector_type(8)));
typedef _Float16 f16x4 __attribute__((ext_vector_type(4)));
typedef float    f32x4 __attribute__((ext_vector_type(4)));

#define B_   64
#define N_   512
#define D_   1024
#define HROWS (B_ * N_)          // 32768
#define EPS_ 1e-5f

// ---------------- elementwise / prep kernels ----------------

__global__ void k_cvt_f16(const float* __restrict__ in, _Float16* __restrict__ out, int n4) {
    int i = blockIdx.x * blockDim.x + threadIdx.x;
    int stride = gridDim.x * blockDim.x;
    const float4* in4 = (const float4*)in;
    for (; i < n4; i += stride) {
        float4 v = in4[i];
        f16x4 o;
        o[0] = (_Float16)v.x; o[1] = (_Float16)v.y;
        o[2] = (_Float16)v.z; o[3] = (_Float16)v.w;
        *(f16x4*)(out + (size_t)i * 4) = o;
    }
}

// W [1024][1024] fp32 -> Wt [1024][1024] f16 (transposed)
__global__ void k_transpose_w(const float* __restrict__ in, _Float16* __restrict__ out) {
    __shared__ float tile[32][33];
    int bx = blockIdx.x * 32;   // col base of in == row base of out
    int by = blockIdx.y * 32;   // row base of in
    int tx = threadIdx.x, ty = threadIdx.y;
    #pragma unroll
    for (int r = 0; r < 32; r += 8)
        tile[ty + r][tx] = in[(size_t)(by + ty + r) * 1024 + bx + tx];
    __syncthreads();
    #pragma unroll
    for (int r = 0; r < 32; r += 8)
        out[(size_t)(bx + ty + r) * 1024 + by + tx] = (_Float16)tile[tx][ty + r];
}

// ---------------- BN stats / normalize ----------------

__global__ void k_bnstats(const float* __restrict__ t, const float* __restrict__ gamma,
                          const float* __restrict__ beta, float* __restrict__ scale,
                          float* __restrict__ shift) {
    const int n = blockIdx.x, tid = threadIdx.x;
    float s = 0.f, s2 = 0.f;
    const float* base = t + (size_t)n * 1024 + tid * 4;
    for (int b = 0; b < 64; ++b) {
        float4 v = *(const float4*)(base + (size_t)b * 512 * 1024);
        s  += v.x + v.y + v.z + v.w;
        s2 += v.x * v.x + v.y * v.y + v.z * v.z + v.w * v.w;
    }
    #pragma unroll
    for (int o = 32; o > 0; o >>= 1) { s += __shfl_down(s, o); s2 += __shfl_down(s2, o); }
    __shared__ float rs_[4], rs2_[4];
    int lane = tid & 63, w = tid >> 6;
    if (lane == 0) { rs_[w] = s; rs2_[w] = s2; }
    __syncthreads();
    if (tid == 0) {
        float S  = rs_[0] + rs_[1] + rs_[2] + rs_[3];
        float S2 = rs2_[0] + rs2_[1] + rs2_[2] + rs2_[3];
        float mean = S * (1.f / 65536.f);
        float var  = S2 * (1.f / 65536.f) - mean * mean;
        float r = rsqrtf(var + EPS_);
        float sc = gamma[n] * r;
        scale[n] = sc;
        shift[n] = beta[n] - mean * sc;
    }
}

// per (b,n) row: normalize + leaky, row-mean, write theta f16 and theta_c f16
__global__ void k_bnorm(const float* __restrict__ t, const float* __restrict__ scale,
                        const float* __restrict__ shift, _Float16* __restrict__ theta,
                        _Float16* __restrict__ thetac) {
    const int row = blockIdx.x, tid = threadIdx.x;
    const int n = row & 511;
    const float sc = scale[n], sh = shift[n];
    float4 v = *(const float4*)(t + (size_t)row * 1024 + tid * 4);
    float a0 = fmaf(v.x, sc, sh); a0 = a0 >= 0.f ? a0 : 0.01f * a0;
    float a1 = fmaf(v.y, sc, sh); a1 = a1 >= 0.f ? a1 : 0.01f * a1;
    float a2 = fmaf(v.z, sc, sh); a2 = a2 >= 0.f ? a2 : 0.01f * a2;
    float a3 = fmaf(v.w, sc, sh); a3 = a3 >= 0.f ? a3 : 0.01f * a3;
    float s = a0 + a1 + a2 + a3;
    #pragma unroll
    for (int o = 32; o > 0; o >>= 1) s += __shfl_down(s, o);
    __shared__ float red[4];
    int lane = tid & 63, w = tid >> 6;
    if (lane == 0) red[w] = s;
    __syncthreads();
    const float mean = (red[0] + red[1] + red[2] + red[3]) * (1.f / 1024.f);
    f16x4 th, tc;
    th[0] = (_Float16)a0; th[1] = (_Float16)a1; th[2] = (_Float16)a2; th[3] = (_Float16)a3;
    tc[0] = (_Float16)(a0 - mean); tc[1] = (_Float16)(a1 - mean);
    tc[2] = (_Float16)(a2 - mean); tc[3] = (_Float16)(a3 - mean);
    *(f16x4*)(theta  + (size_t)row * 1024 + tid * 4) = th;
    *(f16x4*)(thetac + (size_t)row * 1024 + tid * 4) = tc;
}

// ---------------- global softmax (per batch, over 512*512) ----------------

__device__ __forceinline__ unsigned f2key(float f) {
    unsigned u = __float_as_uint(f);
    return (u & 0x80000000u) ? ~u : (u | 0x80000000u);
}
__device__ __forceinline__ float key2f(unsigned k) {
    unsigned u = (k & 0x80000000u) ? (k & 0x7fffffffu) : ~k;
    return __uint_as_float(u);
}

__global__ void k_smax_init(unsigned* __restrict__ mkey, float* __restrict__ ssum) {
    int i = threadIdx.x;
    if (i < 64) { mkey[i] = 0u; ssum[i] = 0.f; }
}

__global__ void k_smax_max(const float* __restrict__ sigma, unsigned* __restrict__ mkey) {
    const int b = blockIdx.y, tid = threadIdx.x;
    float4 v = *(const float4*)(sigma + (size_t)b * 262144 + blockIdx.x * 1024 + tid * 4);
    float m = fmaxf(fmaxf(v.x, v.y), fmaxf(v.z, v.w));
    #pragma unroll
    for (int o = 32; o > 0; o >>= 1) m = fmaxf(m, __shfl_down(m, o));
    __shared__ float red[4];
    int lane = tid & 63, w = tid >> 6;
    if (lane == 0) red[w] = m;
    __syncthreads();
    if (tid == 0)
        atomicMax(mkey + b, f2key(fmaxf(fmaxf(red[0], red[1]), fmaxf(red[2], red[3]))));
}

__global__ void k_smax_sum(const float* __restrict__ sigma, const unsigned* __restrict__ mkey,
                           float* __restrict__ ssum) {
    const int b = blockIdx.y, tid = threadIdx.x;
    const float mx = key2f(mkey[b]);
    float4 v = *(const float4*)(sigma + (size_t)b * 262144 + blockIdx.x * 1024 + tid * 4);
    float s = __expf(v.x - mx) + __expf(v.y - mx) + __expf(v.z - mx) + __expf(v.w - mx);
    #pragma unroll
    for (int o = 32; o > 0; o >>= 1) s += __shfl_down(s, o);
    __shared__ float red[4];
    int lane = tid & 63, w = tid >> 6;
    if (lane == 0) red[w] = s;
    __syncthreads();
    if (tid == 0) atomicAdd(ssum + b, red[0] + red[1] + red[2] + red[3]);
}

__global__ void k_smax_write(const float* __restrict__ sigma, const unsigned* __restrict__ mkey,
                             _Float16* __restrict__ att) {
    const int b = blockIdx.y, tid = threadIdx.x;
    const float mx = key2f(mkey[b]);
    size_t ofs = (size_t)b * 262144 + blockIdx.x * 1024 + tid * 4;
    float4 v = *(const float4*)(sigma + ofs);
    f16x4 o;
    o[0] = (_Float16)__expf(v.x - mx); o[1] = (_Float16)__expf(v.y - mx);
    o[2] = (_Float16)__expf(v.z - mx); o[3] = (_Float16)__expf(v.w - mx);
    *(f16x4*)(att + ofs) = o;
}

// ---------------- shared NT GEMM: C = A * B^T (+epilogue per MODE) ----------------
// MODE 0: t   = xb @ W1t^T + b1          fp32 out, M=32768 N=1024 K=1024
// MODE 1: sig = theta_c @ theta^T / 32768 fp32 out, per batch M=N=512 K=1024
// MODE 2: g_t[b][h][m] = (xb @ W2t^T + b2)^T  f16 out, M=32768 N=1024 K=1024
// MODE 3: ag  = att @ g_t^T * (1/ssum[b])     f16 out, per batch M=512 N=1024 K=512
// MODE 4: out = ag@W3 + xb@W4 + b3 + b4       fp32 out, M=32768 N=1024 K=2048 (concat)

template <int MODE>
__global__ __launch_bounds__(256) void k_gemm(
    const _Float16* __restrict__ A0, const _Float16* __restrict__ A1,
    const _Float16* __restrict__ B0, const _Float16* __restrict__ B1,
    const float* __restrict__ bias0, const float* __restrict__ bias1,
    const float* __restrict__ sumptr, void* __restrict__ outp) {

    constexpr int BK = 32;
    __shared__ _Float16 Al[128 * BK];
    __shared__ _Float16 Bl[128 * BK];

    const int tid = threadIdx.x, lane = tid & 63, w = tid >> 6;
    const int wm = w >> 1, wn = w & 1;
    const int bm = blockIdx.x, bn = blockIdx.y, bz = blockIdx.z;

    int K_, LDA, LDB;
    size_t aOff, bOff;
    if constexpr (MODE == 0 || MODE == 2 || MODE == 4) {
        K_ = (MODE == 4) ? 2048 : 1024; LDA = 1024; LDB = 1024;
        aOff = (size_t)bm * 128 * 1024;
        bOff = (size_t)bn * 128 * 1024;
    } else if constexpr (MODE == 1) {
        K_ = 1024; LDA = 1024; LDB = 1024;
        aOff = ((size_t)bz * 512 + bm * 128) * 1024;
        bOff = ((size_t)bz * 512 + bn * 128) * 1024;
    } else { // MODE 3
        K_ = 512; LDA = 512; LDB = 512;
        aOff = (size_t)bz * 262144 + (size_t)bm * 128 * 512;
        bOff = (size_t)bz * 524288 + (size_t)bn * 128 * 512;
    }

    float oscale = 1.f;
    if constexpr (MODE == 3) oscale = 1.f / sumptr[bz];

    f32x4 acc[4][4] = {};

    for (int k0 = 0; k0 < K_; k0 += BK) {
        const _Float16* As; const _Float16* Bs; int kk = k0;
        if constexpr (MODE == 4) {
            if (k0 < 1024) { As = A0; Bs = B0; }
            else           { As = A1; Bs = B1; kk = k0 - 1024; }
        } else { As = A0; Bs = B0; }

        #pragma unroll
        for (int tt = 0; tt < 2; tt++) {
            int s = tt * 256 + tid, row = s >> 2, kc = s & 3;
            *(uint4*)&Al[row * BK + kc * 8] =
                *(const uint4*)(As + aOff + (size_t)row * LDA + kk + kc * 8);
        }
        #pragma unroll
        for (int tt = 0; tt < 2; tt++) {
            int s = tt * 256 + tid, row = s >> 2, kc = s & 3;
            *(uint4*)&Bl[row * BK + kc * 8] =
                *(const uint4*)(Bs + bOff + (size_t)row * LDB + kk + kc * 8);
        }
        __syncthreads();

        const int lr = lane & 15, kg = lane >> 4;
        f16x8 af[4], bf[4];
        #pragma unroll
        for (int m = 0; m < 4; m++)
            af[m] = *(const f16x8*)&Al[(wm * 64 + m * 16 + lr) * BK + kg * 8];
        #pragma unroll
        for (int n = 0; n < 4; n++)
            bf[n] = *(const f16x8*)&Bl[(wn * 64 + n * 16 + lr) * BK + kg * 8];
        #pragma unroll
        for (int m = 0; m < 4; m++)
            #pragma unroll
            for (int n = 0; n < 4; n++)
                acc[m][n] = __builtin_amdgcn_mfma_f32_16x16x32_f16(af[m], bf[n], acc[m][n], 0, 0, 0);
        __syncthreads();
    }

    // epilogue
    const int lr = lane & 15, kg = lane >> 4;
    #pragma unroll
    for (int m = 0; m < 4; m++) {
        #pragma unroll
        for (int n = 0; n < 4; n++) {
            const int r0 = wm * 64 + m * 16 + kg * 4;
            const int c  = wn * 64 + n * 16 + lr;
            if constexpr (MODE == 0) {
                float* o = (float*)outp;
                const size_t gr0 = (size_t)bm * 128 + r0;
                const int gc = bn * 128 + c;
                const float bias = bias0[gc];
                #pragma unroll
                for (int i = 0; i < 4; i++) o[(gr0 + i) * 1024 + gc] = acc[m][n][i] + bias;
            } else if constexpr (MODE == 1) {
                float* o = (float*)outp + (size_t)bz * 262144;
                const int gr0 = bm * 128 + r0, gc = bn * 128 + c;
                #pragma unroll
                for (int i = 0; i < 4; i++)
                    o[(size_t)(gr0 + i) * 512 + gc] = acc[m][n][i] * (1.f / 32768.f);
            } else if constexpr (MODE == 2) {
                _Float16* o = (_Float16*)outp;
                const int gr0 = bm * 128 + r0;
                const int gc = bn * 128 + c;
                const int bb = gr0 >> 9, mm = gr0 & 511;
                const float bias = bias0[gc];
                f16x4 pk;
                #pragma unroll
                for (int i = 0; i < 4; i++) pk[i] = (_Float16)(acc[m][n][i] + bias);
                *(f16x4*)(o + ((size_t)bb * 1024 + gc) * 512 + mm) = pk;
            } else if constexpr (MODE == 3) {
                _Float16* o = (_Float16*)outp + (size_t)bz * 524288;
                const int gr0 = bm * 128 + r0, gc = bn * 128 + c;
                #pragma unroll
                for (int i = 0; i < 4; i++)
                    o[(size_t)(gr0 + i) * 1024 + gc] = (_Float16)(acc[m][n][i] * oscale);
            } else { // MODE 4
                float* o = (float*)outp;
                const size_t gr0 = (size_t)bm * 128 + r0;
                const int gc = bn * 128 + c;
                const float bias = bias0[gc] + bias1[gc];
                #pragma unroll
                for (int i = 0; i < 4; i++) o[(gr0 + i) * 1024 + gc] = acc[m][n][i] + bias;
            }
        }
    }
}

// ---------------- launcher ----------------

extern "C" void kernel_launch(void* const* d_in, const int* in_sizes, int n_in,
                              void* d_out, int out_size, void* d_ws, size_t ws_size,
                              hipStream_t stream) {
    (void)in_sizes; (void)n_in; (void)out_size; (void)ws_size;
    const float* x     = (const float*)d_in[0];
    const float* W1    = (const float*)d_in[1];
    const float* b1    = (const float*)d_in[2];
    const float* gamma = (const float*)d_in[3];
    const float* beta  = (const float*)d_in[4];
    const float* W2    = (const float*)d_in[5];
    const float* b2    = (const float*)d_in[6];
    const float* W3    = (const float*)d_in[7];
    const float* b3    = (const float*)d_in[8];
    const float* W4    = (const float*)d_in[9];
    const float* b4    = (const float*)d_in[10];

    char* wsb = (char*)d_ws;
    const size_t MB = 1024 * 1024;
    _Float16* xb   = (_Float16*)(wsb);                    // 64 MB
    _Float16* W1t  = (_Float16*)(wsb + 64 * MB);          // 2 MB
    _Float16* W2t  = (_Float16*)(wsb + 66 * MB);
    _Float16* W3t  = (_Float16*)(wsb + 68 * MB);
    _Float16* W4t  = (_Float16*)(wsb + 70 * MB);
    float*    t    = (float*)(wsb + 72 * MB);             // 128 MB
    float*    sigma= (float*)(wsb + 72 * MB);             // alias: t dead after bnorm
    _Float16* att  = (_Float16*)(wsb + 136 * MB);         // alias: inside t region (32 MB)
    _Float16* theta  = (_Float16*)(wsb + 200 * MB);       // 64 MB
    _Float16* thetac = (_Float16*)(wsb + 264 * MB);       // 64 MB
    _Float16* g_t  = theta;                               // alias: theta dead after sigma gemm
    _Float16* ag   = thetac;                              // alias: theta_c dead after sigma gemm
    float*    scl  = (float*)(wsb + 328 * MB);
    float*    shf  = (float*)(wsb + 328 * MB + 4096);
    unsigned* mkey = (unsigned*)(wsb + 328 * MB + 8192);
    float*    ssum = (float*)(wsb + 328 * MB + 8192 + 256);

    // 1. x -> f16
    k_cvt_f16<<<8192, 256, 0, stream>>>(x, xb, (64 * 512 * 1024 * 4) / 4 / 4);
    // 2. transpose weights -> f16 [out][in]
    dim3 tb(32, 8), tg(32, 32);
    k_transpose_w<<<tg, tb, 0, stream>>>(W1, W1t);
    k_transpose_w<<<tg, tb, 0, stream>>>(W2, W2t);
    k_transpose_w<<<tg, tb, 0, stream>>>(W3, W3t);
    k_transpose_w<<<tg, tb, 0, stream>>>(W4, W4t);
    // 3. t = xb @ W1 + b1 (fp32)
    k_gemm<0><<<dim3(256, 8, 1), 256, 0, stream>>>(xb, nullptr, W1t, nullptr, b1, nullptr, nullptr, t);
    // 4. BN stats
    k_bnstats<<<512, 256, 0, stream>>>(t, gamma, beta, scl, shf);
    // 5. normalize + leaky + row-center -> theta, theta_c
    k_bnorm<<<32768, 256, 0, stream>>>(t, scl, shf, theta, thetac);
    // 6. sigma = theta_c @ theta^T / 32768 (per batch)
    k_gemm<1><<<dim3(4, 4, 64), 256, 0, stream>>>(thetac, nullptr, theta, nullptr, nullptr, nullptr, nullptr, sigma);
    // 7-10. global softmax per batch
    k_smax_init<<<1, 64, 0, stream>>>(mkey, ssum);
    k_smax_max<<<dim3(256, 64), 256, 0, stream>>>(sigma, mkey);
    k_smax_sum<<<dim3(256, 64), 256, 0, stream>>>(sigma, mkey, ssum);
    k_smax_write<<<dim3(256, 64), 256, 0, stream>>>(sigma, mkey, att);
    // 11. g_t[b][h][m] = (xb @ W2 + b2)^T
    k_gemm<2><<<dim3(256, 8, 1), 256, 0, stream>>>(xb, nullptr, W2t, nullptr, b2, nullptr, nullptr, g_t);
    // 12. ag = (att @ g) / ssum (per batch)
    k_gemm<3><<<dim3(4, 8, 64), 256, 0, stream>>>(att, nullptr, g_t, nullptr, nullptr, nullptr, ssum, ag);
    // 13. out = ag @ W3 + xb @ W4 + b3 + b4
    k_gemm<4><<<dim3(256, 8, 1), 256, 0, stream>>>(ag, xb, W3t, W4t, b3, b4, nullptr, d_out);
}